// Round 27
// baseline (348.998 us; speedup 1.0000x reference)
//
#include <hip/hip_runtime.h>
#include <hip/hip_bf16.h>

typedef unsigned short u16;
typedef unsigned int u32;
typedef short bf16x8 __attribute__((ext_vector_type(8)));
typedef float f32x4 __attribute__((ext_vector_type(4)));
typedef float f32x16 __attribute__((ext_vector_type(16)));

#define B_ 4
#define S_ 2048
#define E_ 1024
#define H_ 16
#define FF_ 4096
#define M_ 8192  // B*S

__device__ __forceinline__ u16 f2bf(float f) {
    u32 u = __float_as_uint(f);
    u32 r = (u + 0x7FFFu + ((u >> 16) & 1u)) >> 16;
    return (u16)r;
}
__device__ __forceinline__ float bf2f(u16 v) {
    return __uint_as_float(((u32)v) << 16);
}
__device__ __forceinline__ u32 cvtpk(float lo, float hi) {
    u32 r;
    asm("v_cvt_pk_bf16_f32 %0, %1, %2" : "=v"(r) : "v"(lo), "v"(hi));
    return r;
}
__device__ __forceinline__ void pswap(u32& a, u32& b) {
    asm("v_permlane32_swap_b32 %0, %1" : "+v"(a), "+v"(b));
}
__device__ __forceinline__ void gload16(const void* g, void* l) {
    __builtin_amdgcn_global_load_lds(
        (__attribute__((address_space(1))) void*)g,
        (__attribute__((address_space(3))) void*)l, 16, 0, 0);
}
// exact-grade GELU (tanh form, max abs err ~3e-4 << bf16 ULP at threshold)
__device__ __forceinline__ float gelu_f(float v) {
    float y = 0.79788456f * (v + 0.044715f * v * v * v);
    float t = __builtin_amdgcn_exp2f(2.88539008f * y);  // e^{2y}
    float th = 1.0f - 2.0f / (t + 1.0f);
    return 0.5f * v * (1.0f + th);
}

// ---------------- fp32 -> bf16 cast, all 4 weight tensors in one launch ----------------
__global__ __launch_bounds__(256) void cvt4_kernel(const float* __restrict__ s0, u16* __restrict__ d0,
                                                   const float* __restrict__ s1, u16* __restrict__ d1,
                                                   const float* __restrict__ s2, u16* __restrict__ d2,
                                                   const float* __restrict__ s3, u16* __restrict__ d3) {
    int blk = blockIdx.x;
    const float* s; u16* d; int base;
    if (blk < 3072)      { s = s0; d = d0; base = blk; }
    else if (blk < 4096) { s = s1; d = d1; base = blk - 3072; }
    else if (blk < 8192) { s = s2; d = d2; base = blk - 4096; }
    else                 { s = s3; d = d3; base = blk - 8192; }
    int i = base * 256 + threadIdx.x;
    float4 v = ((const float4*)s)[i];
    ushort4 o;
    o.x = f2bf(v.x); o.y = f2bf(v.y); o.z = f2bf(v.z); o.w = f2bf(v.w);
    ((ushort4*)d)[i] = o;
}

// ---------------- V transpose: qkv[b,s][2048+h*64+d] -> vt[(bh*64+d)][s] ----------------
__global__ __launch_bounds__(256) void vtrans_kernel(const u16* __restrict__ qkv,
                                                     u16* __restrict__ vt) {
    __shared__ u16 tile[64 * 67];
    int t = threadIdx.x;
    int st = blockIdx.x;
    int bh = blockIdx.y;
    int b = bh >> 4, h = bh & 15;
    int s0 = st * 64;
    int r = t >> 3, c0 = (t & 7) * 8;
#pragma unroll
    for (int half = 0; half < 2; half++) {
        int rr = r + half * 32;
        const u16* src = qkv + (size_t)(b * S_ + s0 + rr) * 3072 + 2048 + h * 64 + c0;
        uint4 v = *(const uint4*)src;
        u16* pv = (u16*)&v;
#pragma unroll
        for (int e = 0; e < 8; e++) tile[(c0 + e) * 67 + rr] = pv[e];
    }
    __syncthreads();
    int d = t >> 2, ch = t & 3;
    u16 buf[16];
#pragma unroll
    for (int j = 0; j < 16; j++) buf[j] = tile[d * 67 + ch * 16 + j];
    u16* dst = vt + ((size_t)bh * 64 + d) * 2048 + s0 + ch * 16;
    *(uint4*)dst = *(uint4*)&buf[0];
    *(uint4*)(dst + 8) = *(uint4*)&buf[8];
}

// ---------------- LayerNorm (fp32 in -> bf16 out), one row per block ----------------
__global__ __launch_bounds__(256) void ln_kernel(const float* __restrict__ x,
                                                 const float* __restrict__ g,
                                                 const float* __restrict__ bb,
                                                 u16* __restrict__ out) {
    int row = blockIdx.x;
    int t = threadIdx.x;
    const float4* xr = (const float4*)(x + (size_t)row * E_);
    float4 v = xr[t];
    float s = v.x + v.y + v.z + v.w;
    float sq = v.x * v.x + v.y * v.y + v.z * v.z + v.w * v.w;
    for (int o = 1; o < 64; o <<= 1) {
        s += __shfl_xor(s, o, 64);
        sq += __shfl_xor(sq, o, 64);
    }
    __shared__ float ss[4], sqs[4];
    int w = t >> 6, l = t & 63;
    if (l == 0) { ss[w] = s; sqs[w] = sq; }
    __syncthreads();
    s = ss[0] + ss[1] + ss[2] + ss[3];
    sq = sqs[0] + sqs[1] + sqs[2] + sqs[3];
    float mean = s * (1.0f / E_);
    float var = sq * (1.0f / E_) - mean * mean;
    float rstd = rsqrtf(var + 1e-5f);
    float4 gv = ((const float4*)g)[t];
    float4 bv = ((const float4*)bb)[t];
    ushort4 o4;
    o4.x = f2bf((v.x - mean) * rstd * gv.x + bv.x);
    o4.y = f2bf((v.y - mean) * rstd * gv.y + bv.y);
    o4.z = f2bf((v.z - mean) * rstd * gv.z + bv.z);
    o4.w = f2bf((v.w - mean) * rstd * gv.w + bv.w);
    ((ushort4*)(out + (size_t)row * E_))[t] = o4;
}

// ---------------- LayerNorm (bf16 in -> bf16 out), one row per block ----------------
__global__ __launch_bounds__(256) void ln_bf16_kernel(const u16* __restrict__ x,
                                                      const float* __restrict__ g,
                                                      const float* __restrict__ bb,
                                                      u16* __restrict__ out) {
    int row = blockIdx.x;
    int t = threadIdx.x;
    ushort4 xv = ((const ushort4*)(x + (size_t)row * E_))[t];
    float v0 = bf2f(xv.x), v1 = bf2f(xv.y), v2 = bf2f(xv.z), v3 = bf2f(xv.w);
    float s = v0 + v1 + v2 + v3;
    float sq = v0 * v0 + v1 * v1 + v2 * v2 + v3 * v3;
    for (int o = 1; o < 64; o <<= 1) {
        s += __shfl_xor(s, o, 64);
        sq += __shfl_xor(sq, o, 64);
    }
    __shared__ float ss[4], sqs[4];
    int w = t >> 6, l = t & 63;
    if (l == 0) { ss[w] = s; sqs[w] = sq; }
    __syncthreads();
    s = ss[0] + ss[1] + ss[2] + ss[3];
    sq = sqs[0] + sqs[1] + sqs[2] + sqs[3];
    float mean = s * (1.0f / E_);
    float var = sq * (1.0f / E_) - mean * mean;
    float rstd = rsqrtf(var + 1e-5f);
    float4 gv = ((const float4*)g)[t];
    float4 bv = ((const float4*)bb)[t];
    ushort4 o4;
    o4.x = f2bf((v0 - mean) * rstd * gv.x + bv.x);
    o4.y = f2bf((v1 - mean) * rstd * gv.y + bv.y);
    o4.z = f2bf((v2 - mean) * rstd * gv.z + bv.z);
    o4.w = f2bf((v3 - mean) * rstd * gv.w + bv.w);
    ((ushort4*)(out + (size_t)row * E_))[t] = o4;
}

// ---------------- GEMM 256x256, BK=64, 8 waves, MERGED 4-phase counted-vmcnt -----------
// fc1's kernel (m256 path confirmed optimal for K=1024 GELU GEMM).
template <int EPI>
__global__ __launch_bounds__(512) void gemm256m(const u16* __restrict__ A,
                                                const u16* __restrict__ Bt,
                                                const float* __restrict__ bias,
                                                void* __restrict__ outp,
                                                int N, int K) {
    __shared__ u16 ldsA[2 * 2 * 8192];
    __shared__ u16 ldsB[2 * 2 * 8192];
    int t = threadIdx.x;
    int wid = t >> 6, l = t & 63, l15 = l & 15, hi4 = l >> 4;
    int wm = wid >> 2, wn = wid & 3;

    int nwg = gridDim.x;
    int flat = blockIdx.x;
    int swz = (flat & 7) * (nwg >> 3) + (flat >> 3);
    int nx = N >> 8;
    int nxs = nx >> 2;
    int sid = swz >> 4, wi = swz & 15;
    int sidm = sid / nxs, sidn = sid % nxs;
    int m0 = (sidm * 4 + (wi >> 2)) * 256;
    int n0 = (sidn * 4 + (wi & 3)) * 256;
    const size_t Kb = (size_t)K * 2;

    f32x4 acc[8][4];
    f32x4 zf = {0.f, 0.f, 0.f, 0.f};
#pragma unroll
    for (int i = 0; i < 8; i++)
#pragma unroll
        for (int j = 0; j < 4; j++) acc[i][j] = zf;

    auto stageA = [&](int buf, int h, int k0) {
#pragma unroll
        for (int rr = 0; rr < 2; ++rr) {
            int o = t * 16 + rr * 8192;
            int lr = o >> 7;
            int gch = ((o >> 4) & 7) ^ (lr & 7);
            int grow = m0 + (lr >> 6) * 128 + h * 64 + (lr & 63);
            gload16((const char*)A + (size_t)grow * Kb + k0 * 2 + gch * 16,
                    (char*)ldsA + (buf * 2 + h) * 16384 + o);
        }
    };
    auto stageB = [&](int buf, int h, int k0) {
#pragma unroll
        for (int rr = 0; rr < 2; ++rr) {
            int o = t * 16 + rr * 8192;
            int lr = o >> 7;
            int gch = ((o >> 4) & 7) ^ (lr & 7);
            int grow = n0 + (lr >> 5) * 64 + h * 32 + (lr & 31);
            gload16((const char*)Bt + (size_t)grow * Kb + k0 * 2 + gch * 16,
                    (char*)ldsB + (buf * 2 + h) * 16384 + o);
        }
    };

    auto readA = [&](int bq, int mh, bf16x8 (&af)[4][2]) {
#pragma unroll
        for (int mi = 0; mi < 4; mi++)
#pragma unroll
            for (int ks = 0; ks < 2; ks++) {
                int lr = wm * 64 + mi * 16 + l15;
                int ob = lr * 128 + ks * 64 + hi4 * 16;
                af[mi][ks] = *(const bf16x8*)((const char*)ldsA +
                             (bq * 2 + mh) * 16384 + (ob ^ ((lr & 7) << 4)));
            }
    };
    auto readB = [&](int bq, int nh, bf16x8 (&bfr)[2][2]) {
#pragma unroll
        for (int nq = 0; nq < 2; nq++)
#pragma unroll
            for (int ks = 0; ks < 2; ks++) {
                int lr = wn * 32 + nq * 16 + l15;
                int ob = lr * 128 + ks * 64 + hi4 * 16;
                bfr[nq][ks] = *(const bf16x8*)((const char*)ldsB +
                              (bq * 2 + nh) * 16384 + (ob ^ ((lr & 7) << 4)));
            }
    };
    auto mma = [&](bf16x8 (&af)[4][2], bf16x8 (&bfr)[2][2], int mh, int nh) {
#pragma unroll
        for (int mi = 0; mi < 4; mi++)
#pragma unroll
            for (int nq = 0; nq < 2; nq++)
#pragma unroll
                for (int ks = 0; ks < 2; ks++)
                    acc[mh * 4 + mi][nh * 2 + nq] =
                        __builtin_amdgcn_mfma_f32_16x16x32_bf16(
                            af[mi][ks], bfr[nq][ks], acc[mh * 4 + mi][nh * 2 + nq], 0, 0, 0);
    };

#define GWAIT(N)                                            \
    asm volatile("s_waitcnt vmcnt(" #N ")" ::: "memory");   \
    __builtin_amdgcn_sched_barrier(0);
#define PH_MID                                              \
    __builtin_amdgcn_s_barrier();                           \
    asm volatile("s_waitcnt lgkmcnt(0)" ::: "memory");      \
    __builtin_amdgcn_sched_barrier(0);                      \
    __builtin_amdgcn_s_setprio(1);
#define PH_END                                              \
    __builtin_amdgcn_s_setprio(0);                          \
    __builtin_amdgcn_s_barrier();

    int ITERS = K >> 7;
    stageB(0, 0, 0); stageB(0, 1, 0); stageA(0, 0, 0); stageA(0, 1, 0);
    stageB(1, 0, 64); stageB(1, 1, 64); stageA(1, 0, 64);
    GWAIT(6);
    __builtin_amdgcn_s_barrier();
    for (int s = 0; s < ITERS; ++s) {
        int k1 = (2 * s + 1) << 6;
        int k2 = (2 * s + 2) << 6; if (k2 >= K) k2 = 0;
        int k3 = (2 * s + 3) << 6; if (k3 >= K) k3 = 0;
        bf16x8 af[4][2], b0[2][2], b1[2][2];
        readA(0, 0, af); readB(0, 0, b0); readB(0, 1, b1);
        stageA(1, 1, k1);
        PH_MID; mma(af, b0, 0, 0); mma(af, b1, 0, 1); PH_END;
        readA(0, 1, af);
        stageB(0, 0, k2); stageB(0, 1, k2); stageA(0, 0, k2);
        PH_MID; mma(af, b0, 1, 0); mma(af, b1, 1, 1);
        __builtin_amdgcn_s_setprio(0);
        GWAIT(8);
        __builtin_amdgcn_s_barrier();
        readA(1, 0, af); readB(1, 0, b0); readB(1, 1, b1);
        stageA(0, 1, k2);
        PH_MID; mma(af, b0, 0, 0); mma(af, b1, 0, 1);
        __builtin_amdgcn_s_setprio(0);
        GWAIT(8);
        __builtin_amdgcn_s_barrier();
        readA(1, 1, af);
        stageB(1, 0, k3); stageB(1, 1, k3); stageA(1, 0, k3);
        GWAIT(6);
        PH_MID; mma(af, b0, 1, 0); mma(af, b1, 1, 1); PH_END;
    }
    GWAIT(0);
    __builtin_amdgcn_s_barrier();
#undef GWAIT
#undef PH_MID
#undef PH_END

    float bias_v[4];
#pragma unroll
    for (int nf = 0; nf < 4; nf++) bias_v[nf] = bias[n0 + wn * 64 + nf * 16 + l15];

    u16* myl = (wid < 4 ? ldsA : ldsB) + (wid & 3) * 8192;
#pragma unroll
    for (int mf = 0; mf < 8; mf++)
#pragma unroll
        for (int nf = 0; nf < 4; nf++)
#pragma unroll
            for (int j = 0; j < 4; j++) {
                int row = mf * 16 + hi4 * 4 + j;
                int col = nf * 16 + l15;
                float v = acc[mf][nf][j] + bias_v[nf];
                if (EPI == 2) v = gelu_f(v);
                int chunk = ((col >> 3) + (row >> 2)) & 7;
                myl[row * 64 + chunk * 8 + (col & 7)] = f2bf(v);
            }
    u16* out16 = (u16*)outp;
#pragma unroll
    for (int pass = 0; pass < 16; ++pass) {
        int row = pass * 8 + (l >> 3);
        int chunk = ((l & 7) + (row >> 2)) & 7;
        uint4 d = *(const uint4*)&myl[row * 64 + chunk * 8];
        int grow = m0 + wm * 128 + row;
        int gcol = n0 + wn * 64 + (l & 7) * 8;
        *(uint4*)&out16[(size_t)grow * N + gcol] = d;
    }
}

// ---------------- GEMM 256x128, BK=64, 8 waves, 4-phase counted-vmcnt ------------------
// EPI: 0 = bf16 (LDS epilogue, qkv); 3 = bf16 + fp32 resid (wo);
//      4 = fp32 out + bf16 resid (fc2).
template <int EPI>
__global__ __launch_bounds__(512) void gemm256n128(const u16* __restrict__ A,
                                                   const u16* __restrict__ Bt,
                                                   const float* __restrict__ bias,
                                                   void* __restrict__ outp,
                                                   const void* __restrict__ residp,
                                                   int N, int K) {
    __shared__ u16 ldsA[2 * 2 * 8192];
    __shared__ u16 ldsB[2 * 8192];
    int t = threadIdx.x;
    int wid = t >> 6, l = t & 63, l15 = l & 15, hi4 = l >> 4;
    int wm = wid >> 2, wn = wid & 3;

    int nwg = gridDim.x;
    int flat = blockIdx.x;
    int swz = (flat & 7) * (nwg >> 3) + (flat >> 3);
    int nx = N >> 7;
    int nxs = nx >> 2;
    int sid = swz >> 4, wi = swz & 15;
    int sidm = sid / nxs, sidn = sid % nxs;
    int m0 = (sidm * 4 + (wi >> 2)) * 256;
    int n0 = (sidn * 4 + (wi & 3)) * 128;
    const size_t Kb = (size_t)K * 2;

    f32x4 acc[8][2];
    f32x4 zf = {0.f, 0.f, 0.f, 0.f};
#pragma unroll
    for (int i = 0; i < 8; i++)
#pragma unroll
        for (int j = 0; j < 2; j++) acc[i][j] = zf;

    auto stageA = [&](int buf, int h, int k0) {
#pragma unroll
        for (int rr = 0; rr < 2; ++rr) {
            int o = t * 16 + rr * 8192;
            int lr = o >> 7;
            int gch = ((o >> 4) & 7) ^ (lr & 7);
            int grow = m0 + (lr >> 6) * 128 + h * 64 + (lr & 63);
            gload16((const char*)A + (size_t)grow * Kb + k0 * 2 + gch * 16,
                    (char*)ldsA + (buf * 2 + h) * 16384 + o);
        }
    };
    auto stageB = [&](int buf, int k0) {
#pragma unroll
        for (int rr = 0; rr < 2; ++rr) {
            int o = t * 16 + rr * 8192;
            int lr = o >> 7;
            int gch = ((o >> 4) & 7) ^ (lr & 7);
            int grow = n0 + lr;
            gload16((const char*)Bt + (size_t)grow * Kb + k0 * 2 + gch * 16,
                    (char*)ldsB + buf * 16384 + o);
        }
    };

    auto readA = [&](int bq, int mh, bf16x8 (&af)[4][2]) {
#pragma unroll
        for (int mi = 0; mi < 4; mi++)
#pragma unroll
            for (int ks = 0; ks < 2; ks++) {
                int lr = wm * 64 + mi * 16 + l15;
                int ob = lr * 128 + ks * 64 + hi4 * 16;
                af[mi][ks] = *(const bf16x8*)((const char*)ldsA +
                             (bq * 2 + mh) * 16384 + (ob ^ ((lr & 7) << 4)));
            }
    };
    auto readB = [&](int bq, bf16x8 (&bfr)[2][2]) {
#pragma unroll
        for (int nq = 0; nq < 2; nq++)
#pragma unroll
            for (int ks = 0; ks < 2; ks++) {
                int lr = wn * 32 + nq * 16 + l15;
                int ob = lr * 128 + ks * 64 + hi4 * 16;
                bfr[nq][ks] = *(const bf16x8*)((const char*)ldsB +
                              bq * 16384 + (ob ^ ((lr & 7) << 4)));
            }
    };
    auto mma = [&](bf16x8 (&af)[4][2], bf16x8 (&bfr)[2][2], int mh) {
#pragma unroll
        for (int mi = 0; mi < 4; mi++)
#pragma unroll
            for (int nq = 0; nq < 2; nq++)
#pragma unroll
                for (int ks = 0; ks < 2; ks++)
                    acc[mh * 4 + mi][nq] =
                        __builtin_amdgcn_mfma_f32_16x16x32_bf16(
                            af[mi][ks], bfr[nq][ks], acc[mh * 4 + mi][nq], 0, 0, 0);
    };

#define GWAIT(N)                                            \
    asm volatile("s_waitcnt vmcnt(" #N ")" ::: "memory");   \
    __builtin_amdgcn_sched_barrier(0);
#define PH_MID                                              \
    __builtin_amdgcn_s_barrier();                           \
    asm volatile("s_waitcnt lgkmcnt(0)" ::: "memory");      \
    __builtin_amdgcn_sched_barrier(0);                      \
    __builtin_amdgcn_s_setprio(1);
#define PH_END                                              \
    __builtin_amdgcn_s_setprio(0);                          \
    __builtin_amdgcn_s_barrier();

    int ITERS = K >> 7;
    stageB(0, 0); stageA(0, 0, 0); stageA(0, 1, 0);
    stageB(1, 64); stageA(1, 0, 64);
    GWAIT(4);
    __builtin_amdgcn_s_barrier();
    for (int s = 0; s < ITERS; ++s) {
        int k1 = (2 * s + 1) << 6;
        int k2 = (2 * s + 2) << 6; if (k2 >= K) k2 = 0;
        int k3 = (2 * s + 3) << 6; if (k3 >= K) k3 = 0;
        bf16x8 af[4][2], br[2][2];
        readA(0, 0, af); readB(0, br); stageA(1, 1, k1);
        PH_MID; mma(af, br, 0); PH_END;
        readA(0, 1, af); stageB(0, k2); stageA(0, 0, k2); GWAIT(4);
        PH_MID; mma(af, br, 1); PH_END;
        readA(1, 0, af); readB(1, br); stageA(0, 1, k2);
        PH_MID; mma(af, br, 0); PH_END;
        readA(1, 1, af); stageB(1, k3); stageA(1, 0, k3); GWAIT(4);
        PH_MID; mma(af, br, 1); PH_END;
    }
    GWAIT(0);
#undef GWAIT
#undef PH_MID
#undef PH_END

    float bias_v[2];
#pragma unroll
    for (int nq = 0; nq < 2; nq++) bias_v[nq] = bias[n0 + wn * 32 + nq * 16 + l15];

    if constexpr (EPI == 0 || EPI == 3) {
        __builtin_amdgcn_s_barrier();
        u16* myl = ldsA + wid * 4096;
        const float* resf = (const float*)residp;
#pragma unroll
        for (int mf = 0; mf < 8; mf++)
#pragma unroll
            for (int nq = 0; nq < 2; nq++)
#pragma unroll
                for (int j = 0; j < 4; j++) {
                    int row = mf * 16 + hi4 * 4 + j;
                    int col = nq * 16 + l15;
                    float v = acc[mf][nq][j] + bias_v[nq];
                    if (EPI == 3)
                        v += resf[(size_t)(m0 + wm * 128 + row) * N + (n0 + wn * 32 + col)];
                    int chunk = ((col >> 3) + (row >> 2)) & 3;
                    myl[row * 32 + chunk * 8 + (col & 7)] = f2bf(v);
                }
        u16* out16 = (u16*)outp;
#pragma unroll
        for (int pass = 0; pass < 8; ++pass) {
            int row = pass * 16 + (l >> 2);
            int cc = l & 3;
            int chunk = (cc + (row >> 2)) & 3;
            uint4 d = *(const uint4*)&myl[row * 32 + chunk * 8];
            int grow = m0 + wm * 128 + row;
            int gcol = n0 + wn * 32 + cc * 8;
            *(uint4*)&out16[(size_t)grow * N + gcol] = d;
        }
    } else {  // EPI == 4: fp32 out + bf16 resid
        const u16* res16 = (const u16*)residp;
#pragma unroll
        for (int mf = 0; mf < 8; mf++)
#pragma unroll
            for (int nq = 0; nq < 2; nq++)
#pragma unroll
                for (int j = 0; j < 4; j++) {
                    int row = m0 + wm * 128 + mf * 16 + hi4 * 4 + j;
                    int col = n0 + wn * 32 + nq * 16 + l15;
                    size_t idx = (size_t)row * N + col;
                    float v = acc[mf][nq][j] + bias_v[nq] + bf2f(res16[idx]);
                    ((float*)outp)[idx] = v;
                }
    }
}

// ---------------- Flash attention: 4-wave blocks, TRIPLE-buffered shared staging -------
// Round-26 structure + 3-buffer K/V staging: tile jt+2 is issued at the TOP of
// iteration jt (its buffer was freed at jt-1's bottom barrier), adding one full
// compute phase of load lead time. vmcnt(4) after the top-issue leaves exactly
// tiles jt+1, jt+2 in flight -> jt landed. LDS 48KB -> still 2 blocks/CU.
__global__ __launch_bounds__(256) void attn_kernel(const u16* __restrict__ qkv,
                                                   const u16* __restrict__ vt,
                                                   u16* __restrict__ aout) {
    __shared__ u16 Ksb[3 * 4096];
    __shared__ u16 Vsb[3 * 4096];
    int t = threadIdx.x;
    int wv = t >> 6, l = t & 63;
    int q31 = l & 31, hi = l >> 5;
    int flat = blockIdx.x;
    int logical = (flat & 7) * 64 + (flat >> 3);  // XCD x owns 8 bh
    int bh = logical >> 3, p0 = logical & 7;
    int b = bh >> 4, h = bh & 15;

    const float qs = 0.18033688011f;  // log2(e)/sqrt(64)

    int row0 = t >> 3, ch0 = t & 7;
    int gch0 = ch0 ^ (row0 & 7);
    const char* srcK0 = (const char*)(qkv + E_ + (size_t)(b * S_ + row0) * 3072 + h * 64) + gch0 * 16;
    const char* srcV0 = (const char*)(vt + ((size_t)(bh * 64 + row0)) * 2048) + gch0 * 16;

    auto issueK = [&](int buf, int j0) {  // K rows stride 6144 B
        gload16(srcK0 + (size_t)j0 * 6144, (char*)Ksb + buf * 8192 + t * 16);
        gload16(srcK0 + (size_t)j0 * 6144 + 32 * 6144, (char*)Ksb + buf * 8192 + t * 16 + 4096);
    };
    auto issueV = [&](int buf, int j0) {  // vt rows stride 4096 B; j0 = s offset (elems)
        gload16(srcV0 + (size_t)j0 * 2, (char*)Vsb + buf * 8192 + t * 16);
        gload16(srcV0 + (size_t)j0 * 2 + 32 * 4096, (char*)Vsb + buf * 8192 + t * 16 + 4096);
    };

    f32x16 zf16;
#pragma unroll
    for (int r = 0; r < 16; r++) zf16[r] = 0.f;

    for (int half = 0; half < 2; ++half) {
        int qt = half ? (15 - p0) : p0;
        int wrow_min = qt * 128 + wv * 32;
        int rowq = wrow_min + q31;

        // Q fragments, pre-scaled by qs (bf16 repack)
        bf16x8 qreg[4];
        const u16* qbase = qkv + (size_t)(b * S_ + rowq) * 3072 + h * 64 + hi * 8;
#pragma unroll
        for (int g = 0; g < 4; g++) {
            uint4 d16 = *(const uint4*)(qbase + 16 * g);
            u32 uu[4] = {d16.x, d16.y, d16.z, d16.w};
            bf16x8 qv;
#pragma unroll
            for (int e = 0; e < 8; e++) {
                u16 raw = (e & 1) ? (u16)(uu[e >> 1] >> 16) : (u16)(uu[e >> 1] & 0xffffu);
                qv[e] = (short)f2bf(bf2f(raw) * qs);
            }
            qreg[g] = qv;
        }

        f32x16 o0 = zf16, o1 = zf16;
        float lrun = 0.f;

        int ntiles = 2 * qt + 2;
        // prologue: tiles 0 (buf0) and 1 (buf1) in flight
        issueK(0, 0); issueV(0, 0);
        issueK(1, 64); issueV(1, 64);

        int cur = 0;  // buffer of tile jt; cycles 0,1,2
        for (int jt = 0; jt < ntiles; ++jt) {
            int j0 = jt * 64;
            // top-issue tile jt+2 into buffer (cur+2)%3 — freed at jt-1's bottom barrier
            int nxt = cur + 2; if (nxt >= 3) nxt -= 3;
            int nj = (jt + 2 < ntiles) ? (jt + 2) * 64 : 0;  // tail: harmless dummies
            issueK(nxt, nj);
            issueV(nxt, nj);
            asm volatile("s_waitcnt vmcnt(4)" ::: "memory");  // K_jt, V_jt landed
            __builtin_amdgcn_sched_barrier(0);
            __builtin_amdgcn_s_barrier();

            if (j0 <= wrow_min + 31) {
                const u16* Kc = Ksb + cur * 4096;
                const u16* Vc = Vsb + cur * 4096;

                f32x16 s0 = zf16, s1 = zf16;
                __builtin_amdgcn_s_setprio(1);
#pragma unroll
                for (int g = 0; g < 4; g++) {
                    int r0 = q31, r1 = 32 + q31;
                    bf16x8 k0 = *(const bf16x8*)&Kc[((r0 << 6) + hi * 8 + 16 * g) ^ ((r0 & 7) << 3)];
                    bf16x8 k1 = *(const bf16x8*)&Kc[((r1 << 6) + hi * 8 + 16 * g) ^ ((r1 & 7) << 3)];
                    s0 = __builtin_amdgcn_mfma_f32_32x32x16_bf16(k0, qreg[g], s0, 0, 0, 0);
                    s1 = __builtin_amdgcn_mfma_f32_32x32x16_bf16(k1, qreg[g], s1, 0, 0, 0);
                }
                __builtin_amdgcn_s_setprio(0);

                int cb0 = j0 + 4 * hi;
                float sa = 0.f, sb = 0.f, sc2 = 0.f, sd = 0.f;
                if (j0 + 63 > wrow_min) {
#pragma unroll
                    for (int r = 0; r < 16; r++) {
                        const int cc = (r & 3) + 8 * (r >> 2);
                        bool bad0 = (cb0 + cc > rowq) || (r == 15 && hi);
                        bool bad1 = (cb0 + 32 + cc > rowq) || (r == 15 && hi);
                        float p0 = bad0 ? 0.f : __builtin_amdgcn_exp2f(s0[r]);
                        float p1 = bad1 ? 0.f : __builtin_amdgcn_exp2f(s1[r]);
                        s0[r] = p0; s1[r] = p1;
                        if (r & 1) { sb += p0; sd += p1; } else { sa += p0; sc2 += p1; }
                    }
                } else {
#pragma unroll
                    for (int r = 0; r < 16; r++) {
                        float p0 = __builtin_amdgcn_exp2f(s0[r]);
                        float p1 = __builtin_amdgcn_exp2f(s1[r]);
                        if (r == 15 && hi) { p0 = 0.f; p1 = 0.f; }
                        s0[r] = p0; s1[r] = p1;
                        if (r & 1) { sb += p0; sd += p1; } else { sa += p0; sc2 += p1; }
                    }
                }
                lrun += (sa + sb) + (sc2 + sd);

                bf16x8 pa[4];
#pragma unroll
                for (int g = 0; g < 4; g++) {
                    const int bs = (g & 1) * 8;
                    u32 wa, wb, wc, wd;
                    if (g < 2) {
                        wa = cvtpk(s0[bs + 0], s0[bs + 1]);
                        wb = cvtpk(s0[bs + 4], s0[bs + 5]);
                        wc = cvtpk(s0[bs + 2], s0[bs + 3]);
                        wd = cvtpk(s0[bs + 6], s0[bs + 7]);
                    } else {
                        wa = cvtpk(s1[bs + 0], s1[bs + 1]);
                        wb = cvtpk(s1[bs + 4], s1[bs + 5]);
                        wc = cvtpk(s1[bs + 2], s1[bs + 3]);
                        wd = cvtpk(s1[bs + 6], s1[bs + 7]);
                    }
                    pswap(wa, wb);
                    pswap(wc, wd);
                    union { u32 w[4]; bf16x8 f; } u;
                    u.w[0] = wa; u.w[1] = wc; u.w[2] = wb; u.w[3] = wd;
                    pa[g] = u.f;
                }

                __builtin_amdgcn_s_setprio(1);
#pragma unroll
                for (int g = 0; g < 4; g++) {
                    int d0 = q31, d1 = 32 + q31;
                    bf16x8 v0 = *(const bf16x8*)&Vc[((d0 << 6) + hi * 8 + 16 * g) ^ ((d0 & 7) << 3)];
                    bf16x8 v1 = *(const bf16x8*)&Vc[((d1 << 6) + hi * 8 + 16 * g) ^ ((d1 & 7) << 3)];
                    o0 = __builtin_amdgcn_mfma_f32_32x32x16_bf16(v0, pa[g], o0, 0, 0, 0);
                    o1 = __builtin_amdgcn_mfma_f32_32x32x16_bf16(v1, pa[g], o1, 0, 0, 0);
                }
                __builtin_amdgcn_s_setprio(0);
            }

            __builtin_amdgcn_s_barrier();  // all waves done with buf[cur]
            cur = cur + 1; if (cur >= 3) cur = 0;
        }

        lrun += __shfl_xor(lrun, 32, 64);
        float inv = 1.0f / lrun;
        u16* orow = aout + (size_t)(b * S_ + rowq) * E_ + h * 64 + 4 * hi;
#pragma unroll
        for (int r = 0; r < 16; r++) {
            const int cc = (r & 3) + 8 * (r >> 2);
            orow[cc] = f2bf(o0[r] * inv);
            orow[32 + cc] = f2bf(o1[r] * inv);
        }

        if (half == 0) {
            // drain tail dummies before half-1 prologue reuses the buffers
            asm volatile("s_waitcnt vmcnt(0)" ::: "memory");
            __builtin_amdgcn_sched_barrier(0);
            __builtin_amdgcn_s_barrier();
        }
    }
}

extern "C" void kernel_launch(void* const* d_in, const int* in_sizes, int n_in,
                              void* d_out, int out_size, void* d_ws, size_t ws_size,
                              hipStream_t stream) {
    const float* x = (const float*)d_in[0];
    const float* ln1_g = (const float*)d_in[2];
    const float* ln1_b = (const float*)d_in[3];
    const float* ln2_g = (const float*)d_in[4];
    const float* ln2_b = (const float*)d_in[5];
    const float* w_qkv = (const float*)d_in[6];
    const float* b_qkv = (const float*)d_in[7];
    const float* w_o = (const float*)d_in[8];
    const float* b_o = (const float*)d_in[9];
    const float* w_fc1 = (const float*)d_in[10];
    const float* b_fc1 = (const float*)d_in[11];
    const float* w_fc2 = (const float*)d_in[12];
    const float* b_fc2 = (const float*)d_in[13];
    float* out = (float*)d_out;
    char* ws = (char*)d_ws;

    u16* wqkv_bf = (u16*)(ws);                  // 6291456
    u16* wo_bf   = (u16*)(ws + 6291456);        // 2097152
    u16* wfc1_bf = (u16*)(ws + 8388608);        // 8388608
    u16* wfc2_bf = (u16*)(ws + 16777216);       // 8388608
    u16* xn_bf   = (u16*)(ws + 25165824);       // 16777216 (LN1 out; reused as LN2 out)
    u16* qkv_bf  = (u16*)(ws + 41943040);       // 50331648 (reused by ffn1)
    u16* ffn1_bf = (u16*)(ws + 41943040);       // 67108864
    u16* attn_bf = (u16*)(ws + 92274688);       // 16777216
    u16* vtw     = (u16*)(ws + 109051904);      // 16777216 (V^T; dead once attn done)
    u16* x2b     = (u16*)(ws + 125829120);      // 16777216 (bf16 residual stream)
    (void)in_sizes; (void)n_in; (void)out_size; (void)ws_size;

    cvt4_kernel<<<12288, 256, 0, stream>>>(w_qkv, wqkv_bf, w_o, wo_bf,
                                           w_fc1, wfc1_bf, w_fc2, wfc2_bf);

    ln_kernel<<<M_, 256, 0, stream>>>(x, ln1_g, ln1_b, xn_bf);

    gemm256n128<0><<<768, 512, 0, stream>>>(xn_bf, wqkv_bf, b_qkv, qkv_bf, nullptr, 3072, 1024);

    vtrans_kernel<<<dim3(32, 64), 256, 0, stream>>>(qkv_bf, vtw);

    attn_kernel<<<512, 256, 0, stream>>>(qkv_bf, vtw, attn_bf);

    // wo: bf16 x2 = x + attn @ w_o^T + b
    gemm256n128<3><<<256, 512, 0, stream>>>(attn_bf, wo_bf, b_o, x2b, x, 1024, 1024);

    ln_bf16_kernel<<<M_, 256, 0, stream>>>(x2b, ln2_g, ln2_b, xn_bf);

    // fc1 on the m256 path (confirmed optimal)
    gemm256m<2><<<512, 512, 0, stream>>>(xn_bf, wfc1_bf, b_fc1, ffn1_bf, 4096, 1024);

    // fc2: fp32 out = bf16 x2 + ffn1 @ w_fc2^T + b
    gemm256n128<4><<<256, 512, 0, stream>>>(ffn1_bf, wfc2_bf, b_fc2, out, x2b, 1024, 4096);
}

// Round 28
// 347.186 us; speedup vs baseline: 1.0052x; 1.0052x over previous
//
#include <hip/hip_runtime.h>
#include <hip/hip_bf16.h>

typedef unsigned short u16;
typedef unsigned int u32;
typedef short bf16x8 __attribute__((ext_vector_type(8)));
typedef float f32x4 __attribute__((ext_vector_type(4)));
typedef float f32x16 __attribute__((ext_vector_type(16)));

#define B_ 4
#define S_ 2048
#define E_ 1024
#define H_ 16
#define FF_ 4096
#define M_ 8192  // B*S

__device__ __forceinline__ u16 f2bf(float f) {
    u32 u = __float_as_uint(f);
    u32 r = (u + 0x7FFFu + ((u >> 16) & 1u)) >> 16;
    return (u16)r;
}
__device__ __forceinline__ float bf2f(u16 v) {
    return __uint_as_float(((u32)v) << 16);
}
__device__ __forceinline__ u32 cvtpk(float lo, float hi) {
    u32 r;
    asm("v_cvt_pk_bf16_f32 %0, %1, %2" : "=v"(r) : "v"(lo), "v"(hi));
    return r;
}
__device__ __forceinline__ void pswap(u32& a, u32& b) {
    asm("v_permlane32_swap_b32 %0, %1" : "+v"(a), "+v"(b));
}
__device__ __forceinline__ void gload16(const void* g, void* l) {
    __builtin_amdgcn_global_load_lds(
        (__attribute__((address_space(1))) void*)g,
        (__attribute__((address_space(3))) void*)l, 16, 0, 0);
}
// exact-grade GELU (tanh form, max abs err ~3e-4 << bf16 ULP at threshold)
__device__ __forceinline__ float gelu_f(float v) {
    float y = 0.79788456f * (v + 0.044715f * v * v * v);
    float t = __builtin_amdgcn_exp2f(2.88539008f * y);  // e^{2y}
    float th = 1.0f - 2.0f / (t + 1.0f);
    return 0.5f * v * (1.0f + th);
}

// ---------------- fp32 -> bf16 cast, all 4 weight tensors in one launch ----------------
__global__ __launch_bounds__(256) void cvt4_kernel(const float* __restrict__ s0, u16* __restrict__ d0,
                                                   const float* __restrict__ s1, u16* __restrict__ d1,
                                                   const float* __restrict__ s2, u16* __restrict__ d2,
                                                   const float* __restrict__ s3, u16* __restrict__ d3) {
    int blk = blockIdx.x;
    const float* s; u16* d; int base;
    if (blk < 3072)      { s = s0; d = d0; base = blk; }
    else if (blk < 4096) { s = s1; d = d1; base = blk - 3072; }
    else if (blk < 8192) { s = s2; d = d2; base = blk - 4096; }
    else                 { s = s3; d = d3; base = blk - 8192; }
    int i = base * 256 + threadIdx.x;
    float4 v = ((const float4*)s)[i];
    ushort4 o;
    o.x = f2bf(v.x); o.y = f2bf(v.y); o.z = f2bf(v.z); o.w = f2bf(v.w);
    ((ushort4*)d)[i] = o;
}

// ---------------- V transpose: qkv[b,s][2048+h*64+d] -> vt[(bh*64+d)][s] ----------------
__global__ __launch_bounds__(256) void vtrans_kernel(const u16* __restrict__ qkv,
                                                     u16* __restrict__ vt) {
    __shared__ u16 tile[64 * 67];
    int t = threadIdx.x;
    int st = blockIdx.x;
    int bh = blockIdx.y;
    int b = bh >> 4, h = bh & 15;
    int s0 = st * 64;
    int r = t >> 3, c0 = (t & 7) * 8;
#pragma unroll
    for (int half = 0; half < 2; half++) {
        int rr = r + half * 32;
        const u16* src = qkv + (size_t)(b * S_ + s0 + rr) * 3072 + 2048 + h * 64 + c0;
        uint4 v = *(const uint4*)src;
        u16* pv = (u16*)&v;
#pragma unroll
        for (int e = 0; e < 8; e++) tile[(c0 + e) * 67 + rr] = pv[e];
    }
    __syncthreads();
    int d = t >> 2, ch = t & 3;
    u16 buf[16];
#pragma unroll
    for (int j = 0; j < 16; j++) buf[j] = tile[d * 67 + ch * 16 + j];
    u16* dst = vt + ((size_t)bh * 64 + d) * 2048 + s0 + ch * 16;
    *(uint4*)dst = *(uint4*)&buf[0];
    *(uint4*)(dst + 8) = *(uint4*)&buf[8];
}

// ---------------- LayerNorm (fp32 in -> bf16 out), one row per block ----------------
__global__ __launch_bounds__(256) void ln_kernel(const float* __restrict__ x,
                                                 const float* __restrict__ g,
                                                 const float* __restrict__ bb,
                                                 u16* __restrict__ out) {
    int row = blockIdx.x;
    int t = threadIdx.x;
    const float4* xr = (const float4*)(x + (size_t)row * E_);
    float4 v = xr[t];
    float s = v.x + v.y + v.z + v.w;
    float sq = v.x * v.x + v.y * v.y + v.z * v.z + v.w * v.w;
    for (int o = 1; o < 64; o <<= 1) {
        s += __shfl_xor(s, o, 64);
        sq += __shfl_xor(sq, o, 64);
    }
    __shared__ float ss[4], sqs[4];
    int w = t >> 6, l = t & 63;
    if (l == 0) { ss[w] = s; sqs[w] = sq; }
    __syncthreads();
    s = ss[0] + ss[1] + ss[2] + ss[3];
    sq = sqs[0] + sqs[1] + sqs[2] + sqs[3];
    float mean = s * (1.0f / E_);
    float var = sq * (1.0f / E_) - mean * mean;
    float rstd = rsqrtf(var + 1e-5f);
    float4 gv = ((const float4*)g)[t];
    float4 bv = ((const float4*)bb)[t];
    ushort4 o4;
    o4.x = f2bf((v.x - mean) * rstd * gv.x + bv.x);
    o4.y = f2bf((v.y - mean) * rstd * gv.y + bv.y);
    o4.z = f2bf((v.z - mean) * rstd * gv.z + bv.z);
    o4.w = f2bf((v.w - mean) * rstd * gv.w + bv.w);
    ((ushort4*)(out + (size_t)row * E_))[t] = o4;
}

// ---------------- LayerNorm (bf16 in -> bf16 out), one row per block ----------------
__global__ __launch_bounds__(256) void ln_bf16_kernel(const u16* __restrict__ x,
                                                      const float* __restrict__ g,
                                                      const float* __restrict__ bb,
                                                      u16* __restrict__ out) {
    int row = blockIdx.x;
    int t = threadIdx.x;
    ushort4 xv = ((const ushort4*)(x + (size_t)row * E_))[t];
    float v0 = bf2f(xv.x), v1 = bf2f(xv.y), v2 = bf2f(xv.z), v3 = bf2f(xv.w);
    float s = v0 + v1 + v2 + v3;
    float sq = v0 * v0 + v1 * v1 + v2 * v2 + v3 * v3;
    for (int o = 1; o < 64; o <<= 1) {
        s += __shfl_xor(s, o, 64);
        sq += __shfl_xor(sq, o, 64);
    }
    __shared__ float ss[4], sqs[4];
    int w = t >> 6, l = t & 63;
    if (l == 0) { ss[w] = s; sqs[w] = sq; }
    __syncthreads();
    s = ss[0] + ss[1] + ss[2] + ss[3];
    sq = sqs[0] + sqs[1] + sqs[2] + sqs[3];
    float mean = s * (1.0f / E_);
    float var = sq * (1.0f / E_) - mean * mean;
    float rstd = rsqrtf(var + 1e-5f);
    float4 gv = ((const float4*)g)[t];
    float4 bv = ((const float4*)bb)[t];
    ushort4 o4;
    o4.x = f2bf((v0 - mean) * rstd * gv.x + bv.x);
    o4.y = f2bf((v1 - mean) * rstd * gv.y + bv.y);
    o4.z = f2bf((v2 - mean) * rstd * gv.z + bv.z);
    o4.w = f2bf((v3 - mean) * rstd * gv.w + bv.w);
    ((ushort4*)(out + (size_t)row * E_))[t] = o4;
}

// ---------------- GEMM 256x256, BK=64, 8 waves, MERGED 4-phase counted-vmcnt -----------
// fc1's kernel (m256 path confirmed optimal for K=1024 GELU GEMM).
template <int EPI>
__global__ __launch_bounds__(512) void gemm256m(const u16* __restrict__ A,
                                                const u16* __restrict__ Bt,
                                                const float* __restrict__ bias,
                                                void* __restrict__ outp,
                                                int N, int K) {
    __shared__ u16 ldsA[2 * 2 * 8192];
    __shared__ u16 ldsB[2 * 2 * 8192];
    int t = threadIdx.x;
    int wid = t >> 6, l = t & 63, l15 = l & 15, hi4 = l >> 4;
    int wm = wid >> 2, wn = wid & 3;

    int nwg = gridDim.x;
    int flat = blockIdx.x;
    int swz = (flat & 7) * (nwg >> 3) + (flat >> 3);
    int nx = N >> 8;
    int nxs = nx >> 2;
    int sid = swz >> 4, wi = swz & 15;
    int sidm = sid / nxs, sidn = sid % nxs;
    int m0 = (sidm * 4 + (wi >> 2)) * 256;
    int n0 = (sidn * 4 + (wi & 3)) * 256;
    const size_t Kb = (size_t)K * 2;

    f32x4 acc[8][4];
    f32x4 zf = {0.f, 0.f, 0.f, 0.f};
#pragma unroll
    for (int i = 0; i < 8; i++)
#pragma unroll
        for (int j = 0; j < 4; j++) acc[i][j] = zf;

    auto stageA = [&](int buf, int h, int k0) {
#pragma unroll
        for (int rr = 0; rr < 2; ++rr) {
            int o = t * 16 + rr * 8192;
            int lr = o >> 7;
            int gch = ((o >> 4) & 7) ^ (lr & 7);
            int grow = m0 + (lr >> 6) * 128 + h * 64 + (lr & 63);
            gload16((const char*)A + (size_t)grow * Kb + k0 * 2 + gch * 16,
                    (char*)ldsA + (buf * 2 + h) * 16384 + o);
        }
    };
    auto stageB = [&](int buf, int h, int k0) {
#pragma unroll
        for (int rr = 0; rr < 2; ++rr) {
            int o = t * 16 + rr * 8192;
            int lr = o >> 7;
            int gch = ((o >> 4) & 7) ^ (lr & 7);
            int grow = n0 + (lr >> 5) * 64 + h * 32 + (lr & 31);
            gload16((const char*)Bt + (size_t)grow * Kb + k0 * 2 + gch * 16,
                    (char*)ldsB + (buf * 2 + h) * 16384 + o);
        }
    };

    auto readA = [&](int bq, int mh, bf16x8 (&af)[4][2]) {
#pragma unroll
        for (int mi = 0; mi < 4; mi++)
#pragma unroll
            for (int ks = 0; ks < 2; ks++) {
                int lr = wm * 64 + mi * 16 + l15;
                int ob = lr * 128 + ks * 64 + hi4 * 16;
                af[mi][ks] = *(const bf16x8*)((const char*)ldsA +
                             (bq * 2 + mh) * 16384 + (ob ^ ((lr & 7) << 4)));
            }
    };
    auto readB = [&](int bq, int nh, bf16x8 (&bfr)[2][2]) {
#pragma unroll
        for (int nq = 0; nq < 2; nq++)
#pragma unroll
            for (int ks = 0; ks < 2; ks++) {
                int lr = wn * 32 + nq * 16 + l15;
                int ob = lr * 128 + ks * 64 + hi4 * 16;
                bfr[nq][ks] = *(const bf16x8*)((const char*)ldsB +
                              (bq * 2 + nh) * 16384 + (ob ^ ((lr & 7) << 4)));
            }
    };
    auto mma = [&](bf16x8 (&af)[4][2], bf16x8 (&bfr)[2][2], int mh, int nh) {
#pragma unroll
        for (int mi = 0; mi < 4; mi++)
#pragma unroll
            for (int nq = 0; nq < 2; nq++)
#pragma unroll
                for (int ks = 0; ks < 2; ks++)
                    acc[mh * 4 + mi][nh * 2 + nq] =
                        __builtin_amdgcn_mfma_f32_16x16x32_bf16(
                            af[mi][ks], bfr[nq][ks], acc[mh * 4 + mi][nh * 2 + nq], 0, 0, 0);
    };

#define GWAIT(N)                                            \
    asm volatile("s_waitcnt vmcnt(" #N ")" ::: "memory");   \
    __builtin_amdgcn_sched_barrier(0);
#define PH_MID                                              \
    __builtin_amdgcn_s_barrier();                           \
    asm volatile("s_waitcnt lgkmcnt(0)" ::: "memory");      \
    __builtin_amdgcn_sched_barrier(0);                      \
    __builtin_amdgcn_s_setprio(1);
#define PH_END                                              \
    __builtin_amdgcn_s_setprio(0);                          \
    __builtin_amdgcn_s_barrier();

    int ITERS = K >> 7;
    stageB(0, 0, 0); stageB(0, 1, 0); stageA(0, 0, 0); stageA(0, 1, 0);
    stageB(1, 0, 64); stageB(1, 1, 64); stageA(1, 0, 64);
    GWAIT(6);
    __builtin_amdgcn_s_barrier();
    for (int s = 0; s < ITERS; ++s) {
        int k1 = (2 * s + 1) << 6;
        int k2 = (2 * s + 2) << 6; if (k2 >= K) k2 = 0;
        int k3 = (2 * s + 3) << 6; if (k3 >= K) k3 = 0;
        bf16x8 af[4][2], b0[2][2], b1[2][2];
        readA(0, 0, af); readB(0, 0, b0); readB(0, 1, b1);
        stageA(1, 1, k1);
        PH_MID; mma(af, b0, 0, 0); mma(af, b1, 0, 1); PH_END;
        readA(0, 1, af);
        stageB(0, 0, k2); stageB(0, 1, k2); stageA(0, 0, k2);
        PH_MID; mma(af, b0, 1, 0); mma(af, b1, 1, 1);
        __builtin_amdgcn_s_setprio(0);
        GWAIT(8);
        __builtin_amdgcn_s_barrier();
        readA(1, 0, af); readB(1, 0, b0); readB(1, 1, b1);
        stageA(0, 1, k2);
        PH_MID; mma(af, b0, 0, 0); mma(af, b1, 0, 1);
        __builtin_amdgcn_s_setprio(0);
        GWAIT(8);
        __builtin_amdgcn_s_barrier();
        readA(1, 1, af);
        stageB(1, 0, k3); stageB(1, 1, k3); stageA(1, 0, k3);
        GWAIT(6);
        PH_MID; mma(af, b0, 1, 0); mma(af, b1, 1, 1); PH_END;
    }
    GWAIT(0);
    __builtin_amdgcn_s_barrier();
#undef GWAIT
#undef PH_MID
#undef PH_END

    float bias_v[4];
#pragma unroll
    for (int nf = 0; nf < 4; nf++) bias_v[nf] = bias[n0 + wn * 64 + nf * 16 + l15];

    u16* myl = (wid < 4 ? ldsA : ldsB) + (wid & 3) * 8192;
#pragma unroll
    for (int mf = 0; mf < 8; mf++)
#pragma unroll
        for (int nf = 0; nf < 4; nf++)
#pragma unroll
            for (int j = 0; j < 4; j++) {
                int row = mf * 16 + hi4 * 4 + j;
                int col = nf * 16 + l15;
                float v = acc[mf][nf][j] + bias_v[nf];
                if (EPI == 2) v = gelu_f(v);
                int chunk = ((col >> 3) + (row >> 2)) & 7;
                myl[row * 64 + chunk * 8 + (col & 7)] = f2bf(v);
            }
    u16* out16 = (u16*)outp;
#pragma unroll
    for (int pass = 0; pass < 16; ++pass) {
        int row = pass * 8 + (l >> 3);
        int chunk = ((l & 7) + (row >> 2)) & 7;
        uint4 d = *(const uint4*)&myl[row * 64 + chunk * 8];
        int grow = m0 + wm * 128 + row;
        int gcol = n0 + wn * 64 + (l & 7) * 8;
        *(uint4*)&out16[(size_t)grow * N + gcol] = d;
    }
}

// ---------------- GEMM 256x128, BK=64, 8 waves, 4-phase counted-vmcnt ------------------
// EPI: 0 = bf16 (LDS epilogue, qkv); 3 = bf16 + fp32 resid (wo);
//      4 = fp32 out + bf16 resid (fc2).
template <int EPI>
__global__ __launch_bounds__(512) void gemm256n128(const u16* __restrict__ A,
                                                   const u16* __restrict__ Bt,
                                                   const float* __restrict__ bias,
                                                   void* __restrict__ outp,
                                                   const void* __restrict__ residp,
                                                   int N, int K) {
    __shared__ u16 ldsA[2 * 2 * 8192];
    __shared__ u16 ldsB[2 * 8192];
    int t = threadIdx.x;
    int wid = t >> 6, l = t & 63, l15 = l & 15, hi4 = l >> 4;
    int wm = wid >> 2, wn = wid & 3;

    int nwg = gridDim.x;
    int flat = blockIdx.x;
    int swz = (flat & 7) * (nwg >> 3) + (flat >> 3);
    int nx = N >> 7;
    int nxs = nx >> 2;
    int sid = swz >> 4, wi = swz & 15;
    int sidm = sid / nxs, sidn = sid % nxs;
    int m0 = (sidm * 4 + (wi >> 2)) * 256;
    int n0 = (sidn * 4 + (wi & 3)) * 128;
    const size_t Kb = (size_t)K * 2;

    f32x4 acc[8][2];
    f32x4 zf = {0.f, 0.f, 0.f, 0.f};
#pragma unroll
    for (int i = 0; i < 8; i++)
#pragma unroll
        for (int j = 0; j < 2; j++) acc[i][j] = zf;

    auto stageA = [&](int buf, int h, int k0) {
#pragma unroll
        for (int rr = 0; rr < 2; ++rr) {
            int o = t * 16 + rr * 8192;
            int lr = o >> 7;
            int gch = ((o >> 4) & 7) ^ (lr & 7);
            int grow = m0 + (lr >> 6) * 128 + h * 64 + (lr & 63);
            gload16((const char*)A + (size_t)grow * Kb + k0 * 2 + gch * 16,
                    (char*)ldsA + (buf * 2 + h) * 16384 + o);
        }
    };
    auto stageB = [&](int buf, int k0) {
#pragma unroll
        for (int rr = 0; rr < 2; ++rr) {
            int o = t * 16 + rr * 8192;
            int lr = o >> 7;
            int gch = ((o >> 4) & 7) ^ (lr & 7);
            int grow = n0 + lr;
            gload16((const char*)Bt + (size_t)grow * Kb + k0 * 2 + gch * 16,
                    (char*)ldsB + buf * 16384 + o);
        }
    };

    auto readA = [&](int bq, int mh, bf16x8 (&af)[4][2]) {
#pragma unroll
        for (int mi = 0; mi < 4; mi++)
#pragma unroll
            for (int ks = 0; ks < 2; ks++) {
                int lr = wm * 64 + mi * 16 + l15;
                int ob = lr * 128 + ks * 64 + hi4 * 16;
                af[mi][ks] = *(const bf16x8*)((const char*)ldsA +
                             (bq * 2 + mh) * 16384 + (ob ^ ((lr & 7) << 4)));
            }
    };
    auto readB = [&](int bq, bf16x8 (&bfr)[2][2]) {
#pragma unroll
        for (int nq = 0; nq < 2; nq++)
#pragma unroll
            for (int ks = 0; ks < 2; ks++) {
                int lr = wn * 32 + nq * 16 + l15;
                int ob = lr * 128 + ks * 64 + hi4 * 16;
                bfr[nq][ks] = *(const bf16x8*)((const char*)ldsB +
                              bq * 16384 + (ob ^ ((lr & 7) << 4)));
            }
    };
    auto mma = [&](bf16x8 (&af)[4][2], bf16x8 (&bfr)[2][2], int mh) {
#pragma unroll
        for (int mi = 0; mi < 4; mi++)
#pragma unroll
            for (int nq = 0; nq < 2; nq++)
#pragma unroll
                for (int ks = 0; ks < 2; ks++)
                    acc[mh * 4 + mi][nq] =
                        __builtin_amdgcn_mfma_f32_16x16x32_bf16(
                            af[mi][ks], bfr[nq][ks], acc[mh * 4 + mi][nq], 0, 0, 0);
    };

#define GWAIT(N)                                            \
    asm volatile("s_waitcnt vmcnt(" #N ")" ::: "memory");   \
    __builtin_amdgcn_sched_barrier(0);
#define PH_MID                                              \
    __builtin_amdgcn_s_barrier();                           \
    asm volatile("s_waitcnt lgkmcnt(0)" ::: "memory");      \
    __builtin_amdgcn_sched_barrier(0);                      \
    __builtin_amdgcn_s_setprio(1);
#define PH_END                                              \
    __builtin_amdgcn_s_setprio(0);                          \
    __builtin_amdgcn_s_barrier();

    int ITERS = K >> 7;
    stageB(0, 0); stageA(0, 0, 0); stageA(0, 1, 0);
    stageB(1, 64); stageA(1, 0, 64);
    GWAIT(4);
    __builtin_amdgcn_s_barrier();
    for (int s = 0; s < ITERS; ++s) {
        int k1 = (2 * s + 1) << 6;
        int k2 = (2 * s + 2) << 6; if (k2 >= K) k2 = 0;
        int k3 = (2 * s + 3) << 6; if (k3 >= K) k3 = 0;
        bf16x8 af[4][2], br[2][2];
        readA(0, 0, af); readB(0, br); stageA(1, 1, k1);
        PH_MID; mma(af, br, 0); PH_END;
        readA(0, 1, af); stageB(0, k2); stageA(0, 0, k2); GWAIT(4);
        PH_MID; mma(af, br, 1); PH_END;
        readA(1, 0, af); readB(1, br); stageA(0, 1, k2);
        PH_MID; mma(af, br, 0); PH_END;
        readA(1, 1, af); stageB(1, k3); stageA(1, 0, k3); GWAIT(4);
        PH_MID; mma(af, br, 1); PH_END;
    }
    GWAIT(0);
#undef GWAIT
#undef PH_MID
#undef PH_END

    float bias_v[2];
#pragma unroll
    for (int nq = 0; nq < 2; nq++) bias_v[nq] = bias[n0 + wn * 32 + nq * 16 + l15];

    if constexpr (EPI == 0 || EPI == 3) {
        __builtin_amdgcn_s_barrier();
        u16* myl = ldsA + wid * 4096;
        const float* resf = (const float*)residp;
#pragma unroll
        for (int mf = 0; mf < 8; mf++)
#pragma unroll
            for (int nq = 0; nq < 2; nq++)
#pragma unroll
                for (int j = 0; j < 4; j++) {
                    int row = mf * 16 + hi4 * 4 + j;
                    int col = nq * 16 + l15;
                    float v = acc[mf][nq][j] + bias_v[nq];
                    if (EPI == 3)
                        v += resf[(size_t)(m0 + wm * 128 + row) * N + (n0 + wn * 32 + col)];
                    int chunk = ((col >> 3) + (row >> 2)) & 3;
                    myl[row * 32 + chunk * 8 + (col & 7)] = f2bf(v);
                }
        u16* out16 = (u16*)outp;
#pragma unroll
        for (int pass = 0; pass < 8; ++pass) {
            int row = pass * 16 + (l >> 2);
            int cc = l & 3;
            int chunk = (cc + (row >> 2)) & 3;
            uint4 d = *(const uint4*)&myl[row * 32 + chunk * 8];
            int grow = m0 + wm * 128 + row;
            int gcol = n0 + wn * 32 + cc * 8;
            *(uint4*)&out16[(size_t)grow * N + gcol] = d;
        }
    } else {  // EPI == 4: fp32 out + bf16 resid
        const u16* res16 = (const u16*)residp;
#pragma unroll
        for (int mf = 0; mf < 8; mf++)
#pragma unroll
            for (int nq = 0; nq < 2; nq++)
#pragma unroll
                for (int j = 0; j < 4; j++) {
                    int row = m0 + wm * 128 + mf * 16 + hi4 * 4 + j;
                    int col = n0 + wn * 32 + nq * 16 + l15;
                    size_t idx = (size_t)row * N + col;
                    float v = acc[mf][nq][j] + bias_v[nq] + bf2f(res16[idx]);
                    ((float*)outp)[idx] = v;
                }
    }
}

// ---------------- Flash attention: 4-wave blocks, shared K/V staging -------------------
// Round-26 configuration (session best): 512 blocks x 256 thr (4 waves x 32 Q rows).
// Fold pairs (p, 15-p) over 16 Q-tiles of 128 rows -> uniform 34 kv-tile-units/block.
// Each 64x64 K/V tile staged once per 128 Q-rows (2 gloads/thread). Double-buffered,
// loop-top vmcnt(4). Swapped QK^T, max-free exp2 softmax, pre-scaled Q,
// cvt_pk+permlane pack, O^T via mfma(V^T, P^T), wave-uniform masked-tile skip.
__global__ __launch_bounds__(256) void attn_kernel(const u16* __restrict__ qkv,
                                                   const u16* __restrict__ vt,
                                                   u16* __restrict__ aout) {
    __shared__ u16 Ksb[2 * 4096];
    __shared__ u16 Vsb[2 * 4096];
    int t = threadIdx.x;
    int wv = t >> 6, l = t & 63;
    int q31 = l & 31, hi = l >> 5;
    int flat = blockIdx.x;
    int logical = (flat & 7) * 64 + (flat >> 3);  // XCD x owns 8 bh
    int bh = logical >> 3, p0 = logical & 7;
    int b = bh >> 4, h = bh & 15;

    const float qs = 0.18033688011f;  // log2(e)/sqrt(64)

    int row0 = t >> 3, ch0 = t & 7;
    int gch0 = ch0 ^ (row0 & 7);
    const char* srcK0 = (const char*)(qkv + E_ + (size_t)(b * S_ + row0) * 3072 + h * 64) + gch0 * 16;
    const char* srcV0 = (const char*)(vt + ((size_t)(bh * 64 + row0)) * 2048) + gch0 * 16;

    auto issueK = [&](int buf, int j0) {  // K rows stride 6144 B
        gload16(srcK0 + (size_t)j0 * 6144, (char*)Ksb + buf * 8192 + t * 16);
        gload16(srcK0 + (size_t)j0 * 6144 + 32 * 6144, (char*)Ksb + buf * 8192 + t * 16 + 4096);
    };
    auto issueV = [&](int buf, int j0) {  // vt rows stride 4096 B; j0 = s offset (elems)
        gload16(srcV0 + (size_t)j0 * 2, (char*)Vsb + buf * 8192 + t * 16);
        gload16(srcV0 + (size_t)j0 * 2 + 32 * 4096, (char*)Vsb + buf * 8192 + t * 16 + 4096);
    };

    f32x16 zf16;
#pragma unroll
    for (int r = 0; r < 16; r++) zf16[r] = 0.f;

    for (int half = 0; half < 2; ++half) {
        int qt = half ? (15 - p0) : p0;
        int wrow_min = qt * 128 + wv * 32;     // wave-uniform first row
        int rowq = wrow_min + q31;

        // Q fragments, pre-scaled by qs (bf16 repack)
        bf16x8 qreg[4];
        const u16* qbase = qkv + (size_t)(b * S_ + rowq) * 3072 + h * 64 + hi * 8;
#pragma unroll
        for (int g = 0; g < 4; g++) {
            uint4 d16 = *(const uint4*)(qbase + 16 * g);
            u32 uu[4] = {d16.x, d16.y, d16.z, d16.w};
            bf16x8 qv;
#pragma unroll
            for (int e = 0; e < 8; e++) {
                u16 raw = (e & 1) ? (u16)(uu[e >> 1] >> 16) : (u16)(uu[e >> 1] & 0xffffu);
                qv[e] = (short)f2bf(bf2f(raw) * qs);
            }
            qreg[g] = qv;
        }

        f32x16 o0 = zf16, o1 = zf16;
        float lrun = 0.f;

        int ntiles = 2 * qt + 2;  // kv tiles of 64 covering rows < (qt+1)*128
        // prologue: tiles 0 and 1 in flight (8 loads/thread); ntiles >= 2 always
        issueK(0, 0); issueV(0, 0);
        issueK(1, 64); issueV(1, 64);

        for (int jt = 0; jt < ntiles; ++jt) {
            int cur = jt & 1;
            int j0 = jt * 64;
            asm volatile("s_waitcnt vmcnt(4)" ::: "memory");  // K_jt, V_jt landed
            __builtin_amdgcn_sched_barrier(0);
            __builtin_amdgcn_s_barrier();

            if (j0 <= wrow_min + 31) {  // tile not fully causal-masked for this wave
                const u16* Kc = Ksb + cur * 4096;
                const u16* Vc = Vsb + cur * 4096;

                f32x16 s0 = zf16, s1 = zf16;
                __builtin_amdgcn_s_setprio(1);
#pragma unroll
                for (int g = 0; g < 4; g++) {
                    int r0 = q31, r1 = 32 + q31;
                    bf16x8 k0 = *(const bf16x8*)&Kc[((r0 << 6) + hi * 8 + 16 * g) ^ ((r0 & 7) << 3)];
                    bf16x8 k1 = *(const bf16x8*)&Kc[((r1 << 6) + hi * 8 + 16 * g) ^ ((r1 & 7) << 3)];
                    s0 = __builtin_amdgcn_mfma_f32_32x32x16_bf16(k0, qreg[g], s0, 0, 0, 0);
                    s1 = __builtin_amdgcn_mfma_f32_32x32x16_bf16(k1, qreg[g], s1, 0, 0, 0);
                }
                __builtin_amdgcn_s_setprio(0);

                // mask + max-free exp2 + partial row sum
                int cb0 = j0 + 4 * hi;
                float sa = 0.f, sb = 0.f, sc2 = 0.f, sd = 0.f;
                if (j0 + 63 > wrow_min) {  // boundary: causal + periodic
#pragma unroll
                    for (int r = 0; r < 16; r++) {
                        const int cc = (r & 3) + 8 * (r >> 2);
                        bool bad0 = (cb0 + cc > rowq) || (r == 15 && hi);
                        bool bad1 = (cb0 + 32 + cc > rowq) || (r == 15 && hi);
                        float p0 = bad0 ? 0.f : __builtin_amdgcn_exp2f(s0[r]);
                        float p1 = bad1 ? 0.f : __builtin_amdgcn_exp2f(s1[r]);
                        s0[r] = p0; s1[r] = p1;
                        if (r & 1) { sb += p0; sd += p1; } else { sa += p0; sc2 += p1; }
                    }
                } else {  // interior: periodic mask only (reg 15, hi half)
#pragma unroll
                    for (int r = 0; r < 16; r++) {
                        float p0 = __builtin_amdgcn_exp2f(s0[r]);
                        float p1 = __builtin_amdgcn_exp2f(s1[r]);
                        if (r == 15 && hi) { p0 = 0.f; p1 = 0.f; }
                        s0[r] = p0; s1[r] = p1;
                        if (r & 1) { sb += p0; sd += p1; } else { sa += p0; sc2 += p1; }
                    }
                }
                lrun += (sa + sb) + (sc2 + sd);

                bf16x8 pa[4];
#pragma unroll
                for (int g = 0; g < 4; g++) {
                    const int bs = (g & 1) * 8;
                    u32 wa, wb, wc, wd;
                    if (g < 2) {
                        wa = cvtpk(s0[bs + 0], s0[bs + 1]);
                        wb = cvtpk(s0[bs + 4], s0[bs + 5]);
                        wc = cvtpk(s0[bs + 2], s0[bs + 3]);
                        wd = cvtpk(s0[bs + 6], s0[bs + 7]);
                    } else {
                        wa = cvtpk(s1[bs + 0], s1[bs + 1]);
                        wb = cvtpk(s1[bs + 4], s1[bs + 5]);
                        wc = cvtpk(s1[bs + 2], s1[bs + 3]);
                        wd = cvtpk(s1[bs + 6], s1[bs + 7]);
                    }
                    pswap(wa, wb);
                    pswap(wc, wd);
                    union { u32 w[4]; bf16x8 f; } u;
                    u.w[0] = wa; u.w[1] = wc; u.w[2] = wb; u.w[3] = wd;
                    pa[g] = u.f;
                }

                __builtin_amdgcn_s_setprio(1);
#pragma unroll
                for (int g = 0; g < 4; g++) {
                    int d0 = q31, d1 = 32 + q31;
                    bf16x8 v0 = *(const bf16x8*)&Vc[((d0 << 6) + hi * 8 + 16 * g) ^ ((d0 & 7) << 3)];
                    bf16x8 v1 = *(const bf16x8*)&Vc[((d1 << 6) + hi * 8 + 16 * g) ^ ((d1 & 7) << 3)];
                    o0 = __builtin_amdgcn_mfma_f32_32x32x16_bf16(v0, pa[g], o0, 0, 0, 0);
                    o1 = __builtin_amdgcn_mfma_f32_32x32x16_bf16(v1, pa[g], o1, 0, 0, 0);
                }
                __builtin_amdgcn_s_setprio(0);
            }

            __builtin_amdgcn_s_barrier();
            int nj = (jt + 2 < ntiles) ? (jt + 2) * 64 : 0;  // tail: harmless dummies
            issueK(cur, nj);
            issueV(cur, nj);
        }

        lrun += __shfl_xor(lrun, 32, 64);
        float inv = 1.0f / lrun;
        u16* orow = aout + (size_t)(b * S_ + rowq) * E_ + h * 64 + 4 * hi;
#pragma unroll
        for (int r = 0; r < 16; r++) {
            const int cc = (r & 3) + 8 * (r >> 2);
            orow[cc] = f2bf(o0[r] * inv);
            orow[32 + cc] = f2bf(o1[r] * inv);
        }

        if (half == 0) {
            // drain tail dummies before half-1 prologue reuses the buffers
            asm volatile("s_waitcnt vmcnt(0)" ::: "memory");
            __builtin_amdgcn_sched_barrier(0);
            __builtin_amdgcn_s_barrier();
        }
    }
}

extern "C" void kernel_launch(void* const* d_in, const int* in_sizes, int n_in,
                              void* d_out, int out_size, void* d_ws, size_t ws_size,
                              hipStream_t stream) {
    const float* x = (const float*)d_in[0];
    const float* ln1_g = (const float*)d_in[2];
    const float* ln1_b = (const float*)d_in[3];
    const float* ln2_g = (const float*)d_in[4];
    const float* ln2_b = (const float*)d_in[5];
    const float* w_qkv = (const float*)d_in[6];
    const float* b_qkv = (const float*)d_in[7];
    const float* w_o = (const float*)d_in[8];
    const float* b_o = (const float*)d_in[9];
    const float* w_fc1 = (const float*)d_in[10];
    const float* b_fc1 = (const float*)d_in[11];
    const float* w_fc2 = (const float*)d_in[12];
    const float* b_fc2 = (const float*)d_in[13];
    float* out = (float*)d_out;
    char* ws = (char*)d_ws;

    u16* wqkv_bf = (u16*)(ws);                  // 6291456
    u16* wo_bf   = (u16*)(ws + 6291456);        // 2097152
    u16* wfc1_bf = (u16*)(ws + 8388608);        // 8388608
    u16* wfc2_bf = (u16*)(ws + 16777216);       // 8388608
    u16* xn_bf   = (u16*)(ws + 25165824);       // 16777216 (LN1 out; reused as LN2 out)
    u16* qkv_bf  = (u16*)(ws + 41943040);       // 50331648 (reused by ffn1)
    u16* ffn1_bf = (u16*)(ws + 41943040);       // 67108864
    u16* attn_bf = (u16*)(ws + 92274688);       // 16777216
    u16* vtw     = (u16*)(ws + 109051904);      // 16777216 (V^T; dead once attn done)
    u16* x2b     = (u16*)(ws + 125829120);      // 16777216 (bf16 residual stream)
    (void)in_sizes; (void)n_in; (void)out_size; (void)ws_size;

    cvt4_kernel<<<12288, 256, 0, stream>>>(w_qkv, wqkv_bf, w_o, wo_bf,
                                           w_fc1, wfc1_bf, w_fc2, wfc2_bf);

    ln_kernel<<<M_, 256, 0, stream>>>(x, ln1_g, ln1_b, xn_bf);

    gemm256n128<0><<<768, 512, 0, stream>>>(xn_bf, wqkv_bf, b_qkv, qkv_bf, nullptr, 3072, 1024);

    vtrans_kernel<<<dim3(32, 64), 256, 0, stream>>>(qkv_bf, vtw);

    attn_kernel<<<512, 256, 0, stream>>>(qkv_bf, vtw, attn_bf);

    // wo: bf16 x2 = x + attn @ w_o^T + b
    gemm256n128<3><<<256, 512, 0, stream>>>(attn_bf, wo_bf, b_o, x2b, x, 1024, 1024);

    ln_bf16_kernel<<<M_, 256, 0, stream>>>(x2b, ln2_g, ln2_b, xn_bf);

    // fc1 on the m256 path (confirmed optimal)
    gemm256m<2><<<512, 512, 0, stream>>>(xn_bf, wfc1_bf, b_fc1, ffn1_bf, 4096, 1024);

    // fc2: fp32 out = bf16 x2 + ffn1 @ w_fc2^T + b
    gemm256n128<4><<<256, 512, 0, stream>>>(ffn1_bf, wfc2_bf, b_fc2, out, x2b, 1024, 4096);
}